// Round 12
// baseline (298.799 us; speedup 1.0000x reference)
//
#include <hip/hip_runtime.h>
#include <hip/hip_bf16.h>

#define B_ 4
#define N_ 2048
#define M_ 2048
#define D_ 128
#define QBLK 128
#define NTHREADS 256
#define KVBLK 64
#define NTILES 32           // M_/KVBLK per batch
#define TILE_BYTES 16384    // 64*128*2
#define SPLIT_MAX 8
#define SCALE2LOG 2.885390081777927f   // 2/ln2
#define LOG2E 1.4426950408889634f
#define DEFER_THR 11.5424f             // 8/ln2

typedef __attribute__((ext_vector_type(8))) short short8;
typedef __attribute__((ext_vector_type(8))) _Float16 half8;
typedef __attribute__((ext_vector_type(16))) float floatx16;
typedef __attribute__((ext_vector_type(4))) unsigned int u32x4;
typedef unsigned short u16;
typedef unsigned int u32;

__device__ __forceinline__ u16 f2bf(float x) {  // RNE
  u32 u = __builtin_bit_cast(u32, x);
  u32 r = (u + 0x7FFFu + ((u >> 16) & 1u)) >> 16;
  return (u16)r;
}
__device__ __forceinline__ float bf2f(u16 h) {
  u32 u = ((u32)h) << 16;
  return __builtin_bit_cast(float, u);
}
__device__ __forceinline__ u32 cvtpkh(float a, float b) {  // 2xf16 packed, RTZ
  u32 r;
  asm("v_cvt_pkrtz_f16_f32 %0, %1, %2" : "=v"(r) : "v"(a), "v"(b));
  return r;
}

#define GLOAD16(src, dst)                                                     \
  __builtin_amdgcn_global_load_lds(                                           \
      (const __attribute__((address_space(1))) void*)(src),                   \
      (__attribute__((address_space(3))) void*)(dst), 16, 0, 0)

// Device-wide spin barrier. Safe ONLY because the whole grid is co-resident
// (512 blocks x 66KB LDS = exactly 2 blocks/CU on 256 CUs). Counters are
// zeroed by hipMemsetAsync before each launch.
__device__ __forceinline__ void spin_barrier(int* cnt, int target) {
  __threadfence();           // release this block's global stores
  __syncthreads();           // all waves' stores covered by the fence
  if (threadIdx.x == 0) {
    __hip_atomic_fetch_add(cnt, 1, __ATOMIC_ACQ_REL, __HIP_MEMORY_SCOPE_AGENT);
    while (__hip_atomic_load(cnt, __ATOMIC_ACQUIRE,
                             __HIP_MEMORY_SCOPE_AGENT) < target)
      __builtin_amdgcn_s_sleep(2);
  }
  __syncthreads();
  __threadfence();           // acquire other blocks' stores
}

// ---------------- fused kernel: prep -> attn -> merge ------------------------
__global__ __launch_bounds__(NTHREADS, 2) void rbf_fused_kernel(
    const float* __restrict__ q, const float* __restrict__ k,
    const float* __restrict__ v, u16* __restrict__ kf_g,
    u16* __restrict__ vt_g, float* __restrict__ k2_g,
    float* __restrict__ out, u16* __restrict__ Opart,
    float* __restrict__ mpart, float* __restrict__ lpart,
    int* __restrict__ cnt_g, int nsplit, int tiles_per_split)
{
  __shared__ __align__(16) u16 KfL[2][8192];   // 32 KB (aliased in A and C)
  __shared__ __align__(16) u16 VtL[2][8192];   // 32 KB
  __shared__ __align__(16) float k2L[2][64];

  const int tid = threadIdx.x;
  const int nblk = (int)gridDim.x;

  // ================= phase A: prep =================
  // K: fp16 of (2/ln2)*K, row-swizzled 64-row tiles + k2 = ||k||^2/ln2.
  // Units of 256 chunks; 512 units total, grid-strided.
  for (int u = blockIdx.x; u < 512; u += nblk) {
    int gid = u * 256 + tid;
    int row_g = gid >> 4;                    // b*M_ + m
    int j = gid & 15;                        // 16B chunk
    const float* kp = k + (size_t)row_g * D_ + j * 8;
    float4 a = *(const float4*)kp;
    float4 c = *(const float4*)(kp + 4);
    float xs[8] = {a.x, a.y, a.z, a.w, c.x, c.y, c.z, c.w};
    half8 kf;
    float ss = 0.f;
    #pragma unroll
    for (int e = 0; e < 8; ++e) {
      ss += xs[e] * xs[e];
      kf[e] = (_Float16)(SCALE2LOG * xs[e]);
    }
    ss += __shfl_xor(ss, 1);
    ss += __shfl_xor(ss, 2);
    ss += __shfl_xor(ss, 4);
    ss += __shfl_xor(ss, 8);
    if (j == 0) k2_g[row_g] = ss * LOG2E;
    int m = row_g & (M_ - 1);
    int b = row_g >> 11;
    int tile = m >> 6, r = m & 63;
    size_t base = ((size_t)b * NTILES + tile) * TILE_BYTES;
    u32 off = (u32)(r * 256 + j * 16) ^ ((u32)(r & 7) << 4);
    *(half8*)((char*)kf_g + base + off) = kf;
  }
  // V: transpose to Vt[d][k] fp16, row-swizzled 64-row tiles (128 tiles).
  {
    u16* T = (u16*)KfL;                      // [64][136] alias, 17.4 KB
    for (int blk = blockIdx.x; blk < 128; blk += nblk) {
      int b = blk >> 5, tile = blk & 31;
      const float* vp = v + ((size_t)b * M_ + tile * 64) * D_;
      #pragma unroll
      for (int p = 0; p < 8; ++p) {
        int idx = p * 256 + tid;
        int r = idx >> 5, c4 = idx & 31;
        float4 vv = *(const float4*)(vp + (size_t)r * D_ + c4 * 4);
        T[r * 136 + c4 * 4 + 0] = __builtin_bit_cast(u16, (_Float16)vv.x);
        T[r * 136 + c4 * 4 + 1] = __builtin_bit_cast(u16, (_Float16)vv.y);
        T[r * 136 + c4 * 4 + 2] = __builtin_bit_cast(u16, (_Float16)vv.z);
        T[r * 136 + c4 * 4 + 3] = __builtin_bit_cast(u16, (_Float16)vv.w);
      }
      __syncthreads();
      size_t base = (size_t)blk * TILE_BYTES;
      #pragma unroll
      for (int p = 0; p < 4; ++p) {
        int idx = p * 256 + tid;
        int d = idx >> 3, rb = idx & 7;
        short8 s;
        #pragma unroll
        for (int i = 0; i < 8; ++i) s[i] = (short)T[(rb * 8 + i) * 136 + d];
        u32 off = (u32)(d * 128 + rb * 16) ^ ((u32)(d & 7) << 4);
        *(short8*)((char*)vt_g + base + off) = s;
      }
      __syncthreads();
    }
  }

  // ---- Q fragments: independent of prep; hides under prep settle ----
  const int w = tid >> 6;
  const int lane = tid & 63;
  const int qlc = lane & 31;
  const int h = lane >> 5;

  int b, qi, sp;
  {
    int gid = blockIdx.x;
    if (nsplit >= 2) {
      int xcd = gid & 7, slot = gid >> 3;
      int gpx = nsplit >> 1;
      int group = xcd * gpx + (slot >> 4);
      qi = slot & 15;
      b = group & 3;
      sp = group >> 2;
    } else {
      qi = gid & 15;
      b = gid >> 4;
      sp = 0;
    }
  }
  const int qt = qi;
  const int q0 = qt * QBLK;
  const int kt0 = sp * tiles_per_split, kt1 = kt0 + tiles_per_split;

  half8 Qf[8];
  {
    const float* qp = q + ((size_t)b * N_ + q0 + w * 32 + qlc) * D_ + h * 8;
    #pragma unroll
    for (int s = 0; s < 8; ++s) {
      float4 a = *(const float4*)(qp + s * 16);
      float4 c = *(const float4*)(qp + s * 16 + 4);
      Qf[s][0] = (_Float16)a.x; Qf[s][1] = (_Float16)a.y;
      Qf[s][2] = (_Float16)a.z; Qf[s][3] = (_Float16)a.w;
      Qf[s][4] = (_Float16)c.x; Qf[s][5] = (_Float16)c.y;
      Qf[s][6] = (_Float16)c.z; Qf[s][7] = (_Float16)c.w;
    }
  }

  // ================= barrier: prep visible device-wide =================
  spin_barrier(cnt_g, nblk);

  // ================= phase B: attention (R7 core, verbatim) =================
  const char* kf_b = (const char*)kf_g + (size_t)b * NTILES * TILE_BYTES;
  const char* vt_b = (const char*)vt_g + (size_t)b * NTILES * TILE_BYTES;
  const float* k2_b = k2_g + (size_t)b * M_;
  const int so = tid * 16;

  #define STAGE(buf, kt)                                                      \
    do {                                                                      \
      const char* kh_ = kf_b + (size_t)(kt) * TILE_BYTES;                     \
      const char* vt_ = vt_b + (size_t)(kt) * TILE_BYTES;                     \
      char* dk = (char*)KfL[buf];                                             \
      char* dv = (char*)VtL[buf];                                             \
      _Pragma("unroll")                                                       \
      for (int c = 0; c < 4; ++c)                                             \
        GLOAD16(kh_ + c * 4096 + so, dk + c * 4096 + w * 1024);               \
      _Pragma("unroll")                                                       \
      for (int c = 0; c < 4; ++c)                                             \
        GLOAD16(vt_ + c * 4096 + so, dv + c * 4096 + w * 1024);               \
      if (tid < 16)                                                           \
        GLOAD16((const char*)(k2_b + (kt) * KVBLK) + tid * 16,                \
                (char*)k2L[buf]);                                             \
    } while (0)

  STAGE(0, kt0);

  floatx16 o[4];
  #pragma unroll
  for (int dt = 0; dt < 4; ++dt) o[dt] = (floatx16)0.0f;
  float mrun = -1e30f, lrun = 0.f;

  asm volatile("s_waitcnt vmcnt(0)" ::: "memory");
  __syncthreads();

  int pb = 0;
  for (int kt = kt0; kt < kt1; ++kt) {
    if (kt + 1 < kt1) STAGE(pb ^ 1, kt + 1);

    const char* Kb = (const char*)KfL[pb];
    const char* Vb = (const char*)VtL[pb];
    const float* k2p = k2L[pb];

    floatx16 accS0 = (floatx16)0.0f, accS1 = (floatx16)0.0f;
    __builtin_amdgcn_s_setprio(1);
    #pragma unroll
    for (int s = 0; s < 8; ++s) {
      {
        int row = qlc;
        u32 off = ((u32)(row * 256 + s * 32 + h * 16)) ^ ((u32)(row & 7) << 4);
        half8 af = *(const half8*)(Kb + off);
        accS0 = __builtin_amdgcn_mfma_f32_32x32x16_f16(af, Qf[s], accS0, 0, 0, 0);
      }
      {
        int row = 32 + qlc;
        u32 off = ((u32)(row * 256 + s * 32 + h * 16)) ^ ((u32)(row & 7) << 4);
        half8 af = *(const half8*)(Kb + off);
        accS1 = __builtin_amdgcn_mfma_f32_32x32x16_f16(af, Qf[s], accS1, 0, 0, 0);
      }
    }
    __builtin_amdgcn_s_setprio(0);

    float mx = -3e38f;
    #pragma unroll
    for (int ct = 0; ct < 2; ++ct) {
      #pragma unroll
      for (int g = 0; g < 4; ++g) {
        float4 kq = *(const float4*)&k2p[32 * ct + 8 * g + 4 * h];
        if (ct == 0) {
          accS0[4 * g + 0] -= kq.x; accS0[4 * g + 1] -= kq.y;
          accS0[4 * g + 2] -= kq.z; accS0[4 * g + 3] -= kq.w;
          mx = fmaxf(mx, fmaxf(fmaxf(accS0[4 * g], accS0[4 * g + 1]),
                               fmaxf(accS0[4 * g + 2], accS0[4 * g + 3])));
        } else {
          accS1[4 * g + 0] -= kq.x; accS1[4 * g + 1] -= kq.y;
          accS1[4 * g + 2] -= kq.z; accS1[4 * g + 3] -= kq.w;
          mx = fmaxf(mx, fmaxf(fmaxf(accS1[4 * g], accS1[4 * g + 1]),
                               fmaxf(accS1[4 * g + 2], accS1[4 * g + 3])));
        }
      }
    }
    mx = fmaxf(mx, __shfl_xor(mx, 32));
    if (!__all(mx - mrun <= DEFER_THR)) {
      float mnew = fmaxf(mrun, mx);
      float scl = exp2f(mrun - mnew);
      mrun = mnew;
      lrun *= scl;
      #pragma unroll
      for (int i = 0; i < 16; ++i) {
        o[0][i] *= scl; o[1][i] *= scl; o[2][i] *= scl; o[3][i] *= scl;
      }
    }
    float ls = 0.f;
    u32 W[2][4][2];
    #pragma unroll
    for (int ct = 0; ct < 2; ++ct) {
      #pragma unroll
      for (int g = 0; g < 4; ++g) {
        float p0, p1, p2, p3;
        if (ct == 0) {
          p0 = exp2f(accS0[4 * g + 0] - mrun); p1 = exp2f(accS0[4 * g + 1] - mrun);
          p2 = exp2f(accS0[4 * g + 2] - mrun); p3 = exp2f(accS0[4 * g + 3] - mrun);
        } else {
          p0 = exp2f(accS1[4 * g + 0] - mrun); p1 = exp2f(accS1[4 * g + 1] - mrun);
          p2 = exp2f(accS1[4 * g + 2] - mrun); p3 = exp2f(accS1[4 * g + 3] - mrun);
        }
        ls += (p0 + p1) + (p2 + p3);
        W[ct][g][0] = cvtpkh(p0, p1);
        W[ct][g][1] = cvtpkh(p2, p3);
      }
    }
    ls += __shfl_xor(ls, 32);
    lrun += ls;

    u32 X[2][4][2];
    #pragma unroll
    for (int ct = 0; ct < 2; ++ct)
      #pragma unroll
      for (int g = 0; g < 4; ++g) {
        X[ct][g][0] = __shfl_xor(W[ct][g][0], 32);
        X[ct][g][1] = __shfl_xor(W[ct][g][1], 32);
      }

    const bool h0 = (h == 0);
    __builtin_amdgcn_s_setprio(1);
    #pragma unroll
    for (int s2 = 0; s2 < 4; ++s2) {
      const int ct = s2 >> 1, e = s2 & 1;
      u32 w0 = h0 ? W[ct][2 * e][0] : X[ct][2 * e + 1][0];
      u32 w1 = h0 ? W[ct][2 * e][1] : X[ct][2 * e + 1][1];
      u32 w2 = h0 ? X[ct][2 * e][0] : W[ct][2 * e + 1][0];
      u32 w3 = h0 ? X[ct][2 * e][1] : W[ct][2 * e + 1][1];
      half8 pf = __builtin_bit_cast(half8, (u32x4){w0, w1, w2, w3});
      #pragma unroll
      for (int dt = 0; dt < 4; ++dt) {
        int row = dt * 32 + qlc;
        u32 off = ((u32)(row * 128 + s2 * 32 + h * 16)) ^ ((u32)(row & 7) << 4);
        half8 af = *(const half8*)(Vb + off);
        o[dt] = __builtin_amdgcn_mfma_f32_32x32x16_f16(af, pf, o[dt], 0, 0, 0);
      }
    }
    __builtin_amdgcn_s_setprio(0);

    asm volatile("s_waitcnt vmcnt(0)" ::: "memory");
    __syncthreads();
    pb ^= 1;
  }

  const int qt32 = qt * 4 + w;
  if (nsplit == 1) {
    float inv = 1.0f / lrun;
    float* ob = out + ((size_t)b * N_ + q0 + w * 32 + qlc) * D_;
    #pragma unroll
    for (int dt = 0; dt < 4; ++dt)
      #pragma unroll
      for (int r = 0; r < 16; ++r) {
        int d = dt * 32 + (r & 3) + 8 * (r >> 2) + 4 * h;
        ob[d] = o[dt][r] * inv;
      }
    return;  // no merge phase needed
  }
  {
    u16* ob = Opart + ((((size_t)sp * B_ + b) * (N_ / 32) + qt32) * D_) * 32;
    #pragma unroll
    for (int dt = 0; dt < 4; ++dt)
      #pragma unroll
      for (int r = 0; r < 16; ++r) {
        int d = dt * 32 + (r & 3) + 8 * (r >> 2) + 4 * h;
        ob[(size_t)d * 32 + qlc] = f2bf(o[dt][r]);
      }
    if (h == 0) {
      size_t mrow = ((size_t)sp * B_ + b) * N_ + qt32 * 32 + qlc;
      mpart[mrow] = mrun;
      lpart[mrow] = lrun;
    }
  }
  #undef STAGE

  // ================= barrier: partials visible =================
  spin_barrier(cnt_g + 16, nblk);

  // ================= phase C: split merge (grid-strided groups) ============
  {
    float* T2 = (float*)KfL;   // 32x136 f32 alias, 17.4 KB
    for (int g2 = blockIdx.x; g2 < B_ * (N_ / 32); g2 += nblk) {
      const int bb = g2 >> 6, qg = g2 & 63;
      const int qln = tid & 31, dg = tid >> 5;
      const size_t stride = (size_t)B_ * N_;
      const size_t mbase = (size_t)bb * N_ + qg * 32 + qln;
      float mmax = -3e38f;
      for (int s = 0; s < nsplit; ++s)
        mmax = fmaxf(mmax, mpart[s * stride + mbase]);
      float acc[16];
      #pragma unroll
      for (int i = 0; i < 16; ++i) acc[i] = 0.f;
      float lsum = 0.f;
      for (int s = 0; s < nsplit; ++s) {
        float wv = exp2f(mpart[s * stride + mbase] - mmax);
        lsum += wv * lpart[s * stride + mbase];
        const u16* ob = Opart +
            ((((size_t)s * B_ + bb) * (N_ / 32) + qg) * D_ + dg * 16) * 32 + qln;
        #pragma unroll
        for (int dd = 0; dd < 16; ++dd) acc[dd] += wv * bf2f(ob[(size_t)dd * 32]);
      }
      float inv = 1.0f / lsum;
      #pragma unroll
      for (int dd = 0; dd < 16; ++dd) T2[qln * 136 + dg * 16 + dd] = acc[dd] * inv;
      __syncthreads();
      const int r = tid >> 3, seg = tid & 7;
      float* op = out + ((size_t)bb * N_ + qg * 32 + r) * D_ + seg * 16;
      #pragma unroll
      for (int i = 0; i < 4; ++i) {
        float4 v4 = {T2[r * 136 + seg * 16 + 4 * i],
                     T2[r * 136 + seg * 16 + 4 * i + 1],
                     T2[r * 136 + seg * 16 + 4 * i + 2],
                     T2[r * 136 + seg * 16 + 4 * i + 3]};
        *(float4*)(op + 4 * i) = v4;
      }
      __syncthreads();
    }
  }
}

extern "C" void kernel_launch(void* const* d_in, const int* in_sizes, int n_in,
                              void* d_out, int out_size, void* d_ws, size_t ws_size,
                              hipStream_t stream) {
  const float* q = (const float*)d_in[0];
  const float* k = (const float*)d_in[1];
  const float* v = (const float*)d_in[2];
  float* out = (float*)d_out;

  const size_t tileBytesAll = (size_t)B_ * NTILES * TILE_BYTES;  // 2 MB each
  u16* kf_g = (u16*)d_ws;
  u16* vt_g = (u16*)((char*)d_ws + tileBytesAll);
  float* k2_g = (float*)((char*)d_ws + 2 * tileBytesAll);
  const size_t prepBytes = 2 * tileBytesAll + (size_t)B_ * M_ * sizeof(float);

  const size_t perO = (size_t)B_ * N_ * D_ * sizeof(u16);   // bf16 partials
  const size_t perML = 2 * (size_t)B_ * N_ * sizeof(float);
  const size_t cntBytes = 256;
  int nsplit = SPLIT_MAX;
  while (nsplit > 1 &&
         prepBytes + (size_t)nsplit * (perO + perML) + cntBytes > ws_size)
    nsplit >>= 1;

  u16* Opart = (u16*)((char*)d_ws + prepBytes);
  float* mpart = (float*)((char*)d_ws + prepBytes + (size_t)nsplit * perO);
  float* lpart = mpart + (size_t)nsplit * B_ * N_;
  int* cnt_g = (int*)(lpart + (size_t)nsplit * B_ * N_);
  int tiles_per_split = NTILES / nsplit;

  // reset spin-barrier counters every call (graph-capturable async memset)
  hipMemsetAsync(cnt_g, 0, cntBytes, stream);

  rbf_fused_kernel<<<dim3(16 * B_ * nsplit), NTHREADS, 0, stream>>>(
      q, k, v, kf_g, vt_g, k2_g, out, Opart, mpart, lpart, cnt_g, nsplit,
      tiles_per_split);
}

// Round 13
// 38.779 us; speedup vs baseline: 7.7052x; 7.7052x over previous
//
#include <hip/hip_runtime.h>
#include <hip/hip_bf16.h>

#define B_ 4
#define N_ 2048
#define M_ 2048
#define D_ 128
#define QBLK 256
#define NTHREADS 512
#define KVBLK 64
#define NTILES 32           // M_/KVBLK per batch
#define TILE_BYTES 16384    // 64*128*2
#define SPLIT_MAX 8
#define SCALE2LOG 2.885390081777927f   // 2/ln2
#define LOG2E 1.4426950408889634f
#define DEFER_THR 11.5424f             // 8/ln2

typedef __attribute__((ext_vector_type(8))) short short8;
typedef __attribute__((ext_vector_type(8))) _Float16 half8;
typedef __attribute__((ext_vector_type(16))) float floatx16;
typedef __attribute__((ext_vector_type(4))) unsigned int u32x4;
typedef unsigned short u16;
typedef unsigned int u32;

__device__ __forceinline__ u16 f2bf(float x) {  // RNE
  u32 u = __builtin_bit_cast(u32, x);
  u32 r = (u + 0x7FFFu + ((u >> 16) & 1u)) >> 16;
  return (u16)r;
}
__device__ __forceinline__ float bf2f(u16 h) {
  u32 u = ((u32)h) << 16;
  return __builtin_bit_cast(float, u);
}
__device__ __forceinline__ u32 cvtpkh(float a, float b) {  // 2xf16 packed, RTZ
  u32 r;
  asm("v_cvt_pkrtz_f16_f32 %0, %1, %2" : "=v"(r) : "v"(a), "v"(b));
  return r;
}

#define GLOAD16(src, dst)                                                     \
  __builtin_amdgcn_global_load_lds(                                           \
      (const __attribute__((address_space(1))) void*)(src),                   \
      (__attribute__((address_space(3))) void*)(dst), 16, 0, 0)

// ---------------- fused prep (identical to R7) -------------------------------
// blocks [0,512): K -> fp16 of (2/ln2)*K (row-swizzled tiles) + k2=||k||^2/ln2
// blocks [512,640): V -> Vt[d][k] fp16 tiles (row-swizzled)
__global__ __launch_bounds__(256) void prep_kernel(
    const float* __restrict__ k, const float* __restrict__ v,
    u16* __restrict__ kf_g, u16* __restrict__ vt_g, float* __restrict__ k2_g)
{
  __shared__ u16 T[64][136];
  int tid = threadIdx.x;
  if (blockIdx.x < 512) {
    int gid = blockIdx.x * 256 + tid;        // B_*M_*16 threads
    int row_g = gid >> 4;                    // b*M_ + m
    int j = gid & 15;                        // 16B chunk
    const float* kp = k + (size_t)row_g * D_ + j * 8;
    float4 a = *(const float4*)kp;
    float4 c = *(const float4*)(kp + 4);
    float xs[8] = {a.x, a.y, a.z, a.w, c.x, c.y, c.z, c.w};
    half8 kf;
    float ss = 0.f;
    #pragma unroll
    for (int e = 0; e < 8; ++e) {
      ss += xs[e] * xs[e];
      kf[e] = (_Float16)(SCALE2LOG * xs[e]);  // RNE v_cvt_f16_f32
    }
    ss += __shfl_xor(ss, 1);
    ss += __shfl_xor(ss, 2);
    ss += __shfl_xor(ss, 4);
    ss += __shfl_xor(ss, 8);
    if (j == 0) k2_g[row_g] = ss * LOG2E;
    int m = row_g & (M_ - 1);
    int b = row_g >> 11;
    int tile = m >> 6, r = m & 63;
    size_t base = ((size_t)b * NTILES + tile) * TILE_BYTES;
    u32 off = (u32)(r * 256 + j * 16) ^ ((u32)(r & 7) << 4);
    *(half8*)((char*)kf_g + base + off) = kf;
  } else {
    int blk = blockIdx.x - 512;              // B_*NTILES blocks
    int b = blk >> 5, tile = blk & 31;
    const float* vp = v + ((size_t)b * M_ + tile * 64) * D_;
    #pragma unroll
    for (int p = 0; p < 8; ++p) {
      int idx = p * 256 + tid;
      int r = idx >> 5, c4 = idx & 31;
      float4 vv = *(const float4*)(vp + (size_t)r * D_ + c4 * 4);
      T[r][c4 * 4 + 0] = __builtin_bit_cast(u16, (_Float16)vv.x);
      T[r][c4 * 4 + 1] = __builtin_bit_cast(u16, (_Float16)vv.y);
      T[r][c4 * 4 + 2] = __builtin_bit_cast(u16, (_Float16)vv.z);
      T[r][c4 * 4 + 3] = __builtin_bit_cast(u16, (_Float16)vv.w);
    }
    __syncthreads();
    size_t base = (size_t)blk * TILE_BYTES;
    #pragma unroll
    for (int p = 0; p < 4; ++p) {
      int idx = p * 256 + tid;
      int d = idx >> 3, rb = idx & 7;
      short8 s;
      #pragma unroll
      for (int i = 0; i < 8; ++i) s[i] = (short)T[rb * 8 + i][d];
      u32 off = (u32)(d * 128 + rb * 16) ^ ((u32)(d & 7) << 4);
      *(short8*)((char*)vt_g + base + off) = s;
    }
  }
}

// ---------------- main attention: 8 waves x 32 q-rows, 32x32x16 f16 MFMA ----
// Identical per-wave math to R7; 8 waves share each staged K/V tile (halves
// per-CU staging traffic, fewer prologues). 256 blocks = 1/CU, 8 waves/CU.
__global__ __launch_bounds__(NTHREADS, 2) void rbf_attn_kernel(
    const float* __restrict__ q, const u16* __restrict__ kf_g,
    const u16* __restrict__ vt_g, const float* __restrict__ k2_g,
    float* __restrict__ out, u16* __restrict__ Opart,
    float* __restrict__ mpart, float* __restrict__ lpart,
    int nsplit, int tiles_per_split)
{
  __shared__ __align__(16) u16 KfL[2][8192];
  __shared__ __align__(16) u16 VtL[2][8192];
  __shared__ __align__(16) float k2L[2][64];

  const int tid = threadIdx.x;
  const int w = tid >> 6;      // 0..7
  const int lane = tid & 63;
  const int qlc = lane & 31;
  const int h = lane >> 5;

  // XCD-bijective decode: all 8 q-blocks of one (b,sp) KV slice -> one XCD
  int b, qi, sp;
  {
    int gid = blockIdx.x;
    if (nsplit >= 2) {
      int xcd = gid & 7, slot = gid >> 3;
      int gpx = nsplit >> 1;               // (4*nsplit)/8 groups per XCD
      int group = xcd * gpx + (slot >> 3);
      qi = slot & 7;
      b = group & 3;
      sp = group >> 2;
    } else {
      qi = gid & 7;
      b = gid >> 3;
      sp = 0;
    }
  }
  const int qt = qi;
  const int q0 = qt * QBLK;
  const int kt0 = sp * tiles_per_split, kt1 = kt0 + tiles_per_split;

  const char* kf_b = (const char*)kf_g + (size_t)b * NTILES * TILE_BYTES;
  const char* vt_b = (const char*)vt_g + (size_t)b * NTILES * TILE_BYTES;
  const float* k2_b = k2_g + (size_t)b * M_;
  const int so = tid * 16;      // = w*1024 + lane*16, spans 8KB

  #define STAGE(buf, kt)                                                      \
    do {                                                                      \
      const char* kh_ = kf_b + (size_t)(kt) * TILE_BYTES;                     \
      const char* vt_ = vt_b + (size_t)(kt) * TILE_BYTES;                     \
      char* dk = (char*)KfL[buf];                                             \
      char* dv = (char*)VtL[buf];                                             \
      _Pragma("unroll")                                                       \
      for (int c = 0; c < 2; ++c)                                             \
        GLOAD16(kh_ + c * 8192 + so, dk + c * 8192 + w * 1024);               \
      _Pragma("unroll")                                                       \
      for (int c = 0; c < 2; ++c)                                             \
        GLOAD16(vt_ + c * 8192 + so, dv + c * 8192 + w * 1024);               \
      if (tid < 16)                                                           \
        GLOAD16((const char*)(k2_b + (kt) * KVBLK) + tid * 16,                \
                (char*)k2L[buf]);                                             \
    } while (0)

  STAGE(0, kt0);  // prologue prefetch; latency hides under Q conversion

  half8 Qf[8];
  {
    const float* qp = q + ((size_t)b * N_ + q0 + w * 32 + qlc) * D_ + h * 8;
    #pragma unroll
    for (int s = 0; s < 8; ++s) {
      float4 a = *(const float4*)(qp + s * 16);
      float4 c = *(const float4*)(qp + s * 16 + 4);
      Qf[s][0] = (_Float16)a.x; Qf[s][1] = (_Float16)a.y;
      Qf[s][2] = (_Float16)a.z; Qf[s][3] = (_Float16)a.w;
      Qf[s][4] = (_Float16)c.x; Qf[s][5] = (_Float16)c.y;
      Qf[s][6] = (_Float16)c.z; Qf[s][7] = (_Float16)c.w;
    }
  }

  floatx16 o[4];
  #pragma unroll
  for (int dt = 0; dt < 4; ++dt) o[dt] = (floatx16)0.0f;
  float mrun = -1e30f, lrun = 0.f;

  asm volatile("s_waitcnt vmcnt(0)" ::: "memory");
  __syncthreads();

  int pb = 0;
  for (int kt = kt0; kt < kt1; ++kt) {
    if (kt + 1 < kt1) STAGE(pb ^ 1, kt + 1);

    const char* Kb = (const char*)KfL[pb];
    const char* Vb = (const char*)VtL[pb];
    const float* k2p = k2L[pb];

    // ---- QK^T single-pass fp16 ----
    floatx16 accS0 = (floatx16)0.0f, accS1 = (floatx16)0.0f;
    __builtin_amdgcn_s_setprio(1);
    #pragma unroll
    for (int s = 0; s < 8; ++s) {
      {
        int row = qlc;
        u32 off = ((u32)(row * 256 + s * 32 + h * 16)) ^ ((u32)(row & 7) << 4);
        half8 af = *(const half8*)(Kb + off);
        accS0 = __builtin_amdgcn_mfma_f32_32x32x16_f16(af, Qf[s], accS0, 0, 0, 0);
      }
      {
        int row = 32 + qlc;
        u32 off = ((u32)(row * 256 + s * 32 + h * 16)) ^ ((u32)(row & 7) << 4);
        half8 af = *(const half8*)(Kb + off);
        accS1 = __builtin_amdgcn_mfma_f32_32x32x16_f16(af, Qf[s], accS1, 0, 0, 0);
      }
    }
    __builtin_amdgcn_s_setprio(0);

    // ---- lane-local softmax (log2 domain) ----
    float mx = -3e38f;
    #pragma unroll
    for (int ct = 0; ct < 2; ++ct) {
      #pragma unroll
      for (int g = 0; g < 4; ++g) {
        float4 kq = *(const float4*)&k2p[32 * ct + 8 * g + 4 * h];
        if (ct == 0) {
          accS0[4 * g + 0] -= kq.x; accS0[4 * g + 1] -= kq.y;
          accS0[4 * g + 2] -= kq.z; accS0[4 * g + 3] -= kq.w;
          mx = fmaxf(mx, fmaxf(fmaxf(accS0[4 * g], accS0[4 * g + 1]),
                               fmaxf(accS0[4 * g + 2], accS0[4 * g + 3])));
        } else {
          accS1[4 * g + 0] -= kq.x; accS1[4 * g + 1] -= kq.y;
          accS1[4 * g + 2] -= kq.z; accS1[4 * g + 3] -= kq.w;
          mx = fmaxf(mx, fmaxf(fmaxf(accS1[4 * g], accS1[4 * g + 1]),
                               fmaxf(accS1[4 * g + 2], accS1[4 * g + 3])));
        }
      }
    }
    mx = fmaxf(mx, __shfl_xor(mx, 32));
    if (!__all(mx - mrun <= DEFER_THR)) {
      float mnew = fmaxf(mrun, mx);
      float scl = exp2f(mrun - mnew);
      mrun = mnew;
      lrun *= scl;
      #pragma unroll
      for (int i = 0; i < 16; ++i) {
        o[0][i] *= scl; o[1][i] *= scl; o[2][i] *= scl; o[3][i] *= scl;
      }
    }
    float ls = 0.f;
    u32 W[2][4][2];
    #pragma unroll
    for (int ct = 0; ct < 2; ++ct) {
      #pragma unroll
      for (int g = 0; g < 4; ++g) {
        float p0, p1, p2, p3;
        if (ct == 0) {
          p0 = exp2f(accS0[4 * g + 0] - mrun); p1 = exp2f(accS0[4 * g + 1] - mrun);
          p2 = exp2f(accS0[4 * g + 2] - mrun); p3 = exp2f(accS0[4 * g + 3] - mrun);
        } else {
          p0 = exp2f(accS1[4 * g + 0] - mrun); p1 = exp2f(accS1[4 * g + 1] - mrun);
          p2 = exp2f(accS1[4 * g + 2] - mrun); p3 = exp2f(accS1[4 * g + 3] - mrun);
        }
        ls += (p0 + p1) + (p2 + p3);
        W[ct][g][0] = cvtpkh(p0, p1);
        W[ct][g][1] = cvtpkh(p2, p3);
      }
    }
    ls += __shfl_xor(ls, 32);
    lrun += ls;

    u32 X[2][4][2];
    #pragma unroll
    for (int ct = 0; ct < 2; ++ct)
      #pragma unroll
      for (int g = 0; g < 4; ++g) {
        X[ct][g][0] = __shfl_xor(W[ct][g][0], 32);
        X[ct][g][1] = __shfl_xor(W[ct][g][1], 32);
      }

    // ---- PV: O^T += Vt · P^T ----
    const bool h0 = (h == 0);
    __builtin_amdgcn_s_setprio(1);
    #pragma unroll
    for (int s2 = 0; s2 < 4; ++s2) {
      const int ct = s2 >> 1, e = s2 & 1;
      u32 w0 = h0 ? W[ct][2 * e][0] : X[ct][2 * e + 1][0];
      u32 w1 = h0 ? W[ct][2 * e][1] : X[ct][2 * e + 1][1];
      u32 w2 = h0 ? X[ct][2 * e][0] : W[ct][2 * e + 1][0];
      u32 w3 = h0 ? X[ct][2 * e][1] : W[ct][2 * e + 1][1];
      half8 pf = __builtin_bit_cast(half8, (u32x4){w0, w1, w2, w3});
      #pragma unroll
      for (int dt = 0; dt < 4; ++dt) {
        int row = dt * 32 + qlc;
        u32 off = ((u32)(row * 128 + s2 * 32 + h * 16)) ^ ((u32)(row & 7) << 4);
        half8 af = *(const half8*)(Vb + off);
        o[dt] = __builtin_amdgcn_mfma_f32_32x32x16_f16(af, pf, o[dt], 0, 0, 0);
      }
    }
    __builtin_amdgcn_s_setprio(0);

    asm volatile("s_waitcnt vmcnt(0)" ::: "memory");
    __syncthreads();
    pb ^= 1;
  }

  // ---- epilogue: O^T regs -> out / Opart bf16 [sp][b][qt32][d][q] ----
  const int qt32 = qt * 8 + w;
  if (nsplit == 1) {
    float inv = 1.0f / lrun;
    float* ob = out + ((size_t)b * N_ + q0 + w * 32 + qlc) * D_;
    #pragma unroll
    for (int dt = 0; dt < 4; ++dt)
      #pragma unroll
      for (int r = 0; r < 16; ++r) {
        int d = dt * 32 + (r & 3) + 8 * (r >> 2) + 4 * h;
        ob[d] = o[dt][r] * inv;
      }
  } else {
    u16* ob = Opart + ((((size_t)sp * B_ + b) * (N_ / 32) + qt32) * D_) * 32;
    #pragma unroll
    for (int dt = 0; dt < 4; ++dt)
      #pragma unroll
      for (int r = 0; r < 16; ++r) {
        int d = dt * 32 + (r & 3) + 8 * (r >> 2) + 4 * h;
        ob[(size_t)d * 32 + qlc] = f2bf(o[dt][r]);
      }
    if (h == 0) {
      size_t mrow = ((size_t)sp * B_ + b) * N_ + qt32 * 32 + qlc;
      mpart[mrow] = mrun;
      lpart[mrow] = lrun;
    }
  }
  #undef STAGE
}

// ---------------- split merge: 512 blocks, one (group, d-half) each ---------
__global__ __launch_bounds__(256) void rbf_reduce_kernel(
    const u16* __restrict__ Opart, const float* __restrict__ mpart,
    const float* __restrict__ lpart, float* __restrict__ out, int nsplit)
{
  __shared__ float T2[32 * 72];
  const int t = threadIdx.x;
  const int unit = blockIdx.x;
  const int group = unit >> 1, dhalf = unit & 1;
  const int b = group >> 6, qt32 = group & 63;
  const int qln = t & 31, dg = t >> 5;           // 8 d-groups x 8
  const size_t stride = (size_t)B_ * N_;
  const size_t mbase = (size_t)b * N_ + qt32 * 32 + qln;
  float mmax = -3e38f;
  for (int s = 0; s < nsplit; ++s)
    mmax = fmaxf(mmax, mpart[s * stride + mbase]);
  float acc[8];
  #pragma unroll
  for (int i = 0; i < 8; ++i) acc[i] = 0.f;
  float lsum = 0.f;
  for (int s = 0; s < nsplit; ++s) {
    float wv = exp2f(mpart[s * stride + mbase] - mmax);
    lsum += wv * lpart[s * stride + mbase];
    const u16* ob = Opart +
        ((((size_t)s * B_ + b) * (N_ / 32) + qt32) * D_ + dhalf * 64 + dg * 8) * 32 + qln;
    #pragma unroll
    for (int dd = 0; dd < 8; ++dd) acc[dd] += wv * bf2f(ob[(size_t)dd * 32]);
  }
  float inv = 1.0f / lsum;
  #pragma unroll
  for (int dd = 0; dd < 8; ++dd) T2[qln * 72 + dg * 8 + dd] = acc[dd] * inv;
  __syncthreads();
  const int r = t >> 3, seg = t & 7;
  float* op = out + ((size_t)b * N_ + qt32 * 32 + r) * D_ + dhalf * 64 + seg * 8;
  float4 v0 = {T2[r * 72 + seg * 8 + 0], T2[r * 72 + seg * 8 + 1],
               T2[r * 72 + seg * 8 + 2], T2[r * 72 + seg * 8 + 3]};
  float4 v1 = {T2[r * 72 + seg * 8 + 4], T2[r * 72 + seg * 8 + 5],
               T2[r * 72 + seg * 8 + 6], T2[r * 72 + seg * 8 + 7]};
  *(float4*)op = v0;
  *(float4*)(op + 4) = v1;
}

extern "C" void kernel_launch(void* const* d_in, const int* in_sizes, int n_in,
                              void* d_out, int out_size, void* d_ws, size_t ws_size,
                              hipStream_t stream) {
  const float* q = (const float*)d_in[0];
  const float* k = (const float*)d_in[1];
  const float* v = (const float*)d_in[2];
  float* out = (float*)d_out;

  const size_t tileBytesAll = (size_t)B_ * NTILES * TILE_BYTES;  // 2 MB each
  u16* kf_g = (u16*)d_ws;
  u16* vt_g = (u16*)((char*)d_ws + tileBytesAll);
  float* k2_g = (float*)((char*)d_ws + 2 * tileBytesAll);
  const size_t prepBytes = 2 * tileBytesAll + (size_t)B_ * M_ * sizeof(float);

  const size_t perO = (size_t)B_ * N_ * D_ * sizeof(u16);   // bf16 partials
  const size_t perML = 2 * (size_t)B_ * N_ * sizeof(float);
  int nsplit = SPLIT_MAX;
  while (nsplit > 1 && prepBytes + (size_t)nsplit * (perO + perML) > ws_size)
    nsplit >>= 1;

  u16* Opart = (u16*)((char*)d_ws + prepBytes);
  float* mpart = (float*)((char*)d_ws + prepBytes + (size_t)nsplit * perO);
  float* lpart = mpart + (size_t)nsplit * B_ * N_;
  int tiles_per_split = NTILES / nsplit;

  prep_kernel<<<512 + B_ * NTILES, 256, 0, stream>>>(k, v, kf_g, vt_g, k2_g);

  rbf_attn_kernel<<<dim3(8 * B_ * nsplit), NTHREADS, 0, stream>>>(
      q, kf_g, vt_g, k2_g, out, Opart, mpart, lpart, nsplit, tiles_per_split);
  if (nsplit > 1) {
    rbf_reduce_kernel<<<2 * B_ * (N_ / 32), 256, 0, stream>>>(
        Opart, mpart, lpart, out, nsplit);
  }
}

// Round 14
// 38.356 us; speedup vs baseline: 7.7902x; 1.0110x over previous
//
#include <hip/hip_runtime.h>
#include <hip/hip_bf16.h>

#define B_ 4
#define N_ 2048
#define M_ 2048
#define D_ 128
#define QBLK 256
#define NTHREADS 512
#define KVBLK 64
#define NTILES 32           // M_/KVBLK per batch
#define TILE_BYTES 16384    // 64*128*2
#define SPLIT_MAX 8
#define SCALE2LOG 2.885390081777927f   // 2/ln2
#define LOG2E 1.4426950408889634f
#define DEFER_THR 11.5424f             // 8/ln2

typedef __attribute__((ext_vector_type(8))) short short8;
typedef __attribute__((ext_vector_type(8))) _Float16 half8;
typedef __attribute__((ext_vector_type(16))) float floatx16;
typedef __attribute__((ext_vector_type(4))) unsigned int u32x4;
typedef unsigned short u16;
typedef unsigned int u32;

__device__ __forceinline__ u16 f2bf(float x) {  // RNE
  u32 u = __builtin_bit_cast(u32, x);
  u32 r = (u + 0x7FFFu + ((u >> 16) & 1u)) >> 16;
  return (u16)r;
}
__device__ __forceinline__ u32 cvtpkh(float a, float b) {  // 2xf16 packed, RTZ
  u32 r;
  asm("v_cvt_pkrtz_f16_f32 %0, %1, %2" : "=v"(r) : "v"(a), "v"(b));
  return r;
}
__device__ __forceinline__ u32 cvtpkb(float a, float b) {  // 2xbf16 packed, RNE
  u32 r;
  asm("v_cvt_pk_bf16_f32 %0, %1, %2" : "=v"(r) : "v"(a), "v"(b));
  return r;
}
__device__ __forceinline__ float bflo(u32 u) {
  return __builtin_bit_cast(float, u << 16);
}
__device__ __forceinline__ float bfhi(u32 u) {
  return __builtin_bit_cast(float, u & 0xFFFF0000u);
}

#define GLOAD16(src, dst)                                                     \
  __builtin_amdgcn_global_load_lds(                                           \
      (const __attribute__((address_space(1))) void*)(src),                   \
      (__attribute__((address_space(3))) void*)(dst), 16, 0, 0)

// ---------------- fused prep (identical to R13) ------------------------------
__global__ __launch_bounds__(256) void prep_kernel(
    const float* __restrict__ k, const float* __restrict__ v,
    u16* __restrict__ kf_g, u16* __restrict__ vt_g, float* __restrict__ k2_g)
{
  __shared__ u16 T[64][136];
  int tid = threadIdx.x;
  if (blockIdx.x < 512) {
    int gid = blockIdx.x * 256 + tid;        // B_*M_*16 threads
    int row_g = gid >> 4;                    // b*M_ + m
    int j = gid & 15;                        // 16B chunk
    const float* kp = k + (size_t)row_g * D_ + j * 8;
    float4 a = *(const float4*)kp;
    float4 c = *(const float4*)(kp + 4);
    float xs[8] = {a.x, a.y, a.z, a.w, c.x, c.y, c.z, c.w};
    half8 kf;
    float ss = 0.f;
    #pragma unroll
    for (int e = 0; e < 8; ++e) {
      ss += xs[e] * xs[e];
      kf[e] = (_Float16)(SCALE2LOG * xs[e]);  // RNE v_cvt_f16_f32
    }
    ss += __shfl_xor(ss, 1);
    ss += __shfl_xor(ss, 2);
    ss += __shfl_xor(ss, 4);
    ss += __shfl_xor(ss, 8);
    if (j == 0) k2_g[row_g] = ss * LOG2E;
    int m = row_g & (M_ - 1);
    int b = row_g >> 11;
    int tile = m >> 6, r = m & 63;
    size_t base = ((size_t)b * NTILES + tile) * TILE_BYTES;
    u32 off = (u32)(r * 256 + j * 16) ^ ((u32)(r & 7) << 4);
    *(half8*)((char*)kf_g + base + off) = kf;
  } else {
    int blk = blockIdx.x - 512;              // B_*NTILES blocks
    int b = blk >> 5, tile = blk & 31;
    const float* vp = v + ((size_t)b * M_ + tile * 64) * D_;
    #pragma unroll
    for (int p = 0; p < 8; ++p) {
      int idx = p * 256 + tid;
      int r = idx >> 5, c4 = idx & 31;
      float4 vv = *(const float4*)(vp + (size_t)r * D_ + c4 * 4);
      T[r][c4 * 4 + 0] = __builtin_bit_cast(u16, (_Float16)vv.x);
      T[r][c4 * 4 + 1] = __builtin_bit_cast(u16, (_Float16)vv.y);
      T[r][c4 * 4 + 2] = __builtin_bit_cast(u16, (_Float16)vv.z);
      T[r][c4 * 4 + 3] = __builtin_bit_cast(u16, (_Float16)vv.w);
    }
    __syncthreads();
    size_t base = (size_t)blk * TILE_BYTES;
    #pragma unroll
    for (int p = 0; p < 4; ++p) {
      int idx = p * 256 + tid;
      int d = idx >> 3, rb = idx & 7;
      short8 s;
      #pragma unroll
      for (int i = 0; i < 8; ++i) s[i] = (short)T[rb * 8 + i][d];
      u32 off = (u32)(d * 128 + rb * 16) ^ ((u32)(d & 7) << 4);
      *(short8*)((char*)vt_g + base + off) = s;
    }
  }
}

// ---------------- main attention: 8 waves x 32 q-rows (R13 core) ------------
// Epilogue change only: partials stored as packed-bf16 u32 pairs
// Opart32 layout [sp][b][qt32][d2=64][q=32]  (d2 = d/2).
__global__ __launch_bounds__(NTHREADS, 2) void rbf_attn_kernel(
    const float* __restrict__ q, const u16* __restrict__ kf_g,
    const u16* __restrict__ vt_g, const float* __restrict__ k2_g,
    float* __restrict__ out, u32* __restrict__ Opart32,
    float* __restrict__ mpart, float* __restrict__ lpart,
    int nsplit, int tiles_per_split)
{
  __shared__ __align__(16) u16 KfL[2][8192];
  __shared__ __align__(16) u16 VtL[2][8192];
  __shared__ __align__(16) float k2L[2][64];

  const int tid = threadIdx.x;
  const int w = tid >> 6;      // 0..7
  const int lane = tid & 63;
  const int qlc = lane & 31;
  const int h = lane >> 5;

  // XCD-bijective decode: all 8 q-blocks of one (b,sp) KV slice -> one XCD
  int b, qi, sp;
  {
    int gid = blockIdx.x;
    if (nsplit >= 2) {
      int xcd = gid & 7, slot = gid >> 3;
      int gpx = nsplit >> 1;               // (4*nsplit)/8 groups per XCD
      int group = xcd * gpx + (slot >> 3);
      qi = slot & 7;
      b = group & 3;
      sp = group >> 2;
    } else {
      qi = gid & 7;
      b = gid >> 3;
      sp = 0;
    }
  }
  const int qt = qi;
  const int q0 = qt * QBLK;
  const int kt0 = sp * tiles_per_split, kt1 = kt0 + tiles_per_split;

  const char* kf_b = (const char*)kf_g + (size_t)b * NTILES * TILE_BYTES;
  const char* vt_b = (const char*)vt_g + (size_t)b * NTILES * TILE_BYTES;
  const float* k2_b = k2_g + (size_t)b * M_;
  const int so = tid * 16;      // = w*1024 + lane*16, spans 8KB

  #define STAGE(buf, kt)                                                      \
    do {                                                                      \
      const char* kh_ = kf_b + (size_t)(kt) * TILE_BYTES;                     \
      const char* vt_ = vt_b + (size_t)(kt) * TILE_BYTES;                     \
      char* dk = (char*)KfL[buf];                                             \
      char* dv = (char*)VtL[buf];                                             \
      _Pragma("unroll")                                                       \
      for (int c = 0; c < 2; ++c)                                             \
        GLOAD16(kh_ + c * 8192 + so, dk + c * 8192 + w * 1024);               \
      _Pragma("unroll")                                                       \
      for (int c = 0; c < 2; ++c)                                             \
        GLOAD16(vt_ + c * 8192 + so, dv + c * 8192 + w * 1024);               \
      if (tid < 16)                                                           \
        GLOAD16((const char*)(k2_b + (kt) * KVBLK) + tid * 16,                \
                (char*)k2L[buf]);                                             \
    } while (0)

  STAGE(0, kt0);  // prologue prefetch; latency hides under Q conversion

  half8 Qf[8];
  {
    const float* qp = q + ((size_t)b * N_ + q0 + w * 32 + qlc) * D_ + h * 8;
    #pragma unroll
    for (int s = 0; s < 8; ++s) {
      float4 a = *(const float4*)(qp + s * 16);
      float4 c = *(const float4*)(qp + s * 16 + 4);
      Qf[s][0] = (_Float16)a.x; Qf[s][1] = (_Float16)a.y;
      Qf[s][2] = (_Float16)a.z; Qf[s][3] = (_Float16)a.w;
      Qf[s][4] = (_Float16)c.x; Qf[s][5] = (_Float16)c.y;
      Qf[s][6] = (_Float16)c.z; Qf[s][7] = (_Float16)c.w;
    }
  }

  floatx16 o[4];
  #pragma unroll
  for (int dt = 0; dt < 4; ++dt) o[dt] = (floatx16)0.0f;
  float mrun = -1e30f, lrun = 0.f;

  asm volatile("s_waitcnt vmcnt(0)" ::: "memory");
  __syncthreads();

  int pb = 0;
  for (int kt = kt0; kt < kt1; ++kt) {
    if (kt + 1 < kt1) STAGE(pb ^ 1, kt + 1);

    const char* Kb = (const char*)KfL[pb];
    const char* Vb = (const char*)VtL[pb];
    const float* k2p = k2L[pb];

    // ---- QK^T single-pass fp16 ----
    floatx16 accS0 = (floatx16)0.0f, accS1 = (floatx16)0.0f;
    __builtin_amdgcn_s_setprio(1);
    #pragma unroll
    for (int s = 0; s < 8; ++s) {
      {
        int row = qlc;
        u32 off = ((u32)(row * 256 + s * 32 + h * 16)) ^ ((u32)(row & 7) << 4);
        half8 af = *(const half8*)(Kb + off);
        accS0 = __builtin_amdgcn_mfma_f32_32x32x16_f16(af, Qf[s], accS0, 0, 0, 0);
      }
      {
        int row = 32 + qlc;
        u32 off = ((u32)(row * 256 + s * 32 + h * 16)) ^ ((u32)(row & 7) << 4);
        half8 af = *(const half8*)(Kb + off);
        accS1 = __builtin_amdgcn_mfma_f32_32x32x16_f16(af, Qf[s], accS1, 0, 0, 0);
      }
    }
    __builtin_amdgcn_s_setprio(0);

    // ---- lane-local softmax (log2 domain) ----
    float mx = -3e38f;
    #pragma unroll
    for (int ct = 0; ct < 2; ++ct) {
      #pragma unroll
      for (int g = 0; g < 4; ++g) {
        float4 kq = *(const float4*)&k2p[32 * ct + 8 * g + 4 * h];
        if (ct == 0) {
          accS0[4 * g + 0] -= kq.x; accS0[4 * g + 1] -= kq.y;
          accS0[4 * g + 2] -= kq.z; accS0[4 * g + 3] -= kq.w;
          mx = fmaxf(mx, fmaxf(fmaxf(accS0[4 * g], accS0[4 * g + 1]),
                               fmaxf(accS0[4 * g + 2], accS0[4 * g + 3])));
        } else {
          accS1[4 * g + 0] -= kq.x; accS1[4 * g + 1] -= kq.y;
          accS1[4 * g + 2] -= kq.z; accS1[4 * g + 3] -= kq.w;
          mx = fmaxf(mx, fmaxf(fmaxf(accS1[4 * g], accS1[4 * g + 1]),
                               fmaxf(accS1[4 * g + 2], accS1[4 * g + 3])));
        }
      }
    }
    mx = fmaxf(mx, __shfl_xor(mx, 32));
    if (!__all(mx - mrun <= DEFER_THR)) {
      float mnew = fmaxf(mrun, mx);
      float scl = exp2f(mrun - mnew);
      mrun = mnew;
      lrun *= scl;
      #pragma unroll
      for (int i = 0; i < 16; ++i) {
        o[0][i] *= scl; o[1][i] *= scl; o[2][i] *= scl; o[3][i] *= scl;
      }
    }
    float ls = 0.f;
    u32 W[2][4][2];
    #pragma unroll
    for (int ct = 0; ct < 2; ++ct) {
      #pragma unroll
      for (int g = 0; g < 4; ++g) {
        float p0, p1, p2, p3;
        if (ct == 0) {
          p0 = exp2f(accS0[4 * g + 0] - mrun); p1 = exp2f(accS0[4 * g + 1] - mrun);
          p2 = exp2f(accS0[4 * g + 2] - mrun); p3 = exp2f(accS0[4 * g + 3] - mrun);
        } else {
          p0 = exp2f(accS1[4 * g + 0] - mrun); p1 = exp2f(accS1[4 * g + 1] - mrun);
          p2 = exp2f(accS1[4 * g + 2] - mrun); p3 = exp2f(accS1[4 * g + 3] - mrun);
        }
        ls += (p0 + p1) + (p2 + p3);
        W[ct][g][0] = cvtpkh(p0, p1);
        W[ct][g][1] = cvtpkh(p2, p3);
      }
    }
    ls += __shfl_xor(ls, 32);
    lrun += ls;

    u32 X[2][4][2];
    #pragma unroll
    for (int ct = 0; ct < 2; ++ct)
      #pragma unroll
      for (int g = 0; g < 4; ++g) {
        X[ct][g][0] = __shfl_xor(W[ct][g][0], 32);
        X[ct][g][1] = __shfl_xor(W[ct][g][1], 32);
      }

    // ---- PV: O^T += Vt · P^T ----
    const bool h0 = (h == 0);
    __builtin_amdgcn_s_setprio(1);
    #pragma unroll
    for (int s2 = 0; s2 < 4; ++s2) {
      const int ct = s2 >> 1, e = s2 & 1;
      u32 w0 = h0 ? W[ct][2 * e][0] : X[ct][2 * e + 1][0];
      u32 w1 = h0 ? W[ct][2 * e][1] : X[ct][2 * e + 1][1];
      u32 w2 = h0 ? X[ct][2 * e][0] : W[ct][2 * e + 1][0];
      u32 w3 = h0 ? X[ct][2 * e][1] : W[ct][2 * e + 1][1];
      half8 pf = __builtin_bit_cast(half8, (u32x4){w0, w1, w2, w3});
      #pragma unroll
      for (int dt = 0; dt < 4; ++dt) {
        int row = dt * 32 + qlc;
        u32 off = ((u32)(row * 128 + s2 * 32 + h * 16)) ^ ((u32)(row & 7) << 4);
        half8 af = *(const half8*)(Vb + off);
        o[dt] = __builtin_amdgcn_mfma_f32_32x32x16_f16(af, pf, o[dt], 0, 0, 0);
      }
    }
    __builtin_amdgcn_s_setprio(0);

    asm volatile("s_waitcnt vmcnt(0)" ::: "memory");
    __syncthreads();
    pb ^= 1;
  }

  // ---- epilogue: O^T regs -> out / Opart32 packed-bf16 pairs ----
  const int qt32 = qt * 8 + w;
  if (nsplit == 1) {
    float inv = 1.0f / lrun;
    float* ob = out + ((size_t)b * N_ + q0 + w * 32 + qlc) * D_;
    #pragma unroll
    for (int dt = 0; dt < 4; ++dt)
      #pragma unroll
      for (int r = 0; r < 16; ++r) {
        int d = dt * 32 + (r & 3) + 8 * (r >> 2) + 4 * h;
        ob[d] = o[dt][r] * inv;
      }
  } else {
    // o[dt][2j],o[dt][2j+1] <-> d,d+1 with d2 = dt*16 + (j&1) + 4*(j>>1) + 2h
    u32* ob = Opart32 +
        ((((size_t)sp * B_ + b) * (N_ / 32) + qt32) * (D_ / 2)) * 32 + qlc;
    #pragma unroll
    for (int dt = 0; dt < 4; ++dt)
      #pragma unroll
      for (int j = 0; j < 8; ++j) {
        int d2 = dt * 16 + (j & 1) + 4 * (j >> 1) + 2 * h;
        ob[(size_t)d2 * 32] = cvtpkb(o[dt][2 * j], o[dt][2 * j + 1]);
      }
    if (h == 0) {
      size_t mrow = ((size_t)sp * B_ + b) * N_ + qt32 * 32 + qlc;
      mpart[mrow] = mrun;
      lpart[mrow] = lrun;
    }
  }
  #undef STAGE
}

// ---------------- split merge: 512 blocks, one (group, d-half) each ---------
__global__ __launch_bounds__(256) void rbf_reduce_kernel(
    const u32* __restrict__ Opart32, const float* __restrict__ mpart,
    const float* __restrict__ lpart, float* __restrict__ out, int nsplit)
{
  __shared__ float T2[32 * 72];
  const int t = threadIdx.x;
  const int unit = blockIdx.x;
  const int group = unit >> 1, dhalf = unit & 1;
  const int b = group >> 6, qt32 = group & 63;
  const int qln = t & 31, dg = t >> 5;           // 8 d-groups x 8 d's
  const size_t stride = (size_t)B_ * N_;
  const size_t mbase = (size_t)b * N_ + qt32 * 32 + qln;
  float mmax = -3e38f;
  for (int s = 0; s < nsplit; ++s)
    mmax = fmaxf(mmax, mpart[s * stride + mbase]);
  float acc[8];
  #pragma unroll
  for (int i = 0; i < 8; ++i) acc[i] = 0.f;
  float lsum = 0.f;
  for (int s = 0; s < nsplit; ++s) {
    float wv = exp2f(mpart[s * stride + mbase] - mmax);
    lsum += wv * lpart[s * stride + mbase];
    const u32* ob = Opart32 +
        ((((size_t)s * B_ + b) * (N_ / 32) + qt32) * (D_ / 2) +
         dhalf * 32 + dg * 4) * 32 + qln;
    #pragma unroll
    for (int i = 0; i < 4; ++i) {
      u32 u = ob[(size_t)i * 32];
      acc[2 * i + 0] += wv * bflo(u);
      acc[2 * i + 1] += wv * bfhi(u);
    }
  }
  float inv = 1.0f / lsum;
  #pragma unroll
  for (int dd = 0; dd < 8; ++dd) T2[qln * 72 + dg * 8 + dd] = acc[dd] * inv;
  __syncthreads();
  const int r = t >> 3, seg = t & 7;
  float* op = out + ((size_t)b * N_ + qt32 * 32 + r) * D_ + dhalf * 64 + seg * 8;
  float4 v0 = {T2[r * 72 + seg * 8 + 0], T2[r * 72 + seg * 8 + 1],
               T2[r * 72 + seg * 8 + 2], T2[r * 72 + seg * 8 + 3]};
  float4 v1 = {T2[r * 72 + seg * 8 + 4], T2[r * 72 + seg * 8 + 5],
               T2[r * 72 + seg * 8 + 6], T2[r * 72 + seg * 8 + 7]};
  *(float4*)op = v0;
  *(float4*)(op + 4) = v1;
}

extern "C" void kernel_launch(void* const* d_in, const int* in_sizes, int n_in,
                              void* d_out, int out_size, void* d_ws, size_t ws_size,
                              hipStream_t stream) {
  const float* q = (const float*)d_in[0];
  const float* k = (const float*)d_in[1];
  const float* v = (const float*)d_in[2];
  float* out = (float*)d_out;

  const size_t tileBytesAll = (size_t)B_ * NTILES * TILE_BYTES;  // 2 MB each
  u16* kf_g = (u16*)d_ws;
  u16* vt_g = (u16*)((char*)d_ws + tileBytesAll);
  float* k2_g = (float*)((char*)d_ws + 2 * tileBytesAll);
  const size_t prepBytes = 2 * tileBytesAll + (size_t)B_ * M_ * sizeof(float);

  const size_t perO = (size_t)B_ * N_ * D_ * sizeof(u16);   // packed bf16 pairs
  const size_t perML = 2 * (size_t)B_ * N_ * sizeof(float);
  int nsplit = SPLIT_MAX;
  while (nsplit > 1 && prepBytes + (size_t)nsplit * (perO + perML) > ws_size)
    nsplit >>= 1;

  u32* Opart32 = (u32*)((char*)d_ws + prepBytes);
  float* mpart = (float*)((char*)d_ws + prepBytes + (size_t)nsplit * perO);
  float* lpart = mpart + (size_t)nsplit * B_ * N_;
  int tiles_per_split = NTILES / nsplit;

  prep_kernel<<<512 + B_ * NTILES, 256, 0, stream>>>(k, v, kf_g, vt_g, k2_g);

  rbf_attn_kernel<<<dim3(8 * B_ * nsplit), NTHREADS, 0, stream>>>(
      q, kf_g, vt_g, k2_g, out, Opart32, mpart, lpart, nsplit, tiles_per_split);
  if (nsplit > 1) {
    rbf_reduce_kernel<<<2 * B_ * (N_ / 32), 256, 0, stream>>>(
        Opart32, mpart, lpart, out, nsplit);
  }
}

// Round 15
// 36.529 us; speedup vs baseline: 8.1798x; 1.0500x over previous
//
#include <hip/hip_runtime.h>
#include <hip/hip_bf16.h>

#define B_ 4
#define N_ 2048
#define M_ 2048
#define D_ 128
#define QBLK 256
#define NTHREADS 512
#define KVBLK 64
#define NTILES 32           // M_/KVBLK per batch
#define TILE_BYTES 16384    // 64*128*2
#define SPLIT_MAX 8
#define SCALE2LOG 2.885390081777927f   // 2/ln2
#define LOG2E 1.4426950408889634f
#define DEFER_THR 11.5424f             // 8/ln2

typedef __attribute__((ext_vector_type(8))) short short8;
typedef __attribute__((ext_vector_type(8))) _Float16 half8;
typedef __attribute__((ext_vector_type(16))) float floatx16;
typedef __attribute__((ext_vector_type(4))) unsigned int u32x4;
typedef unsigned short u16;
typedef unsigned int u32;

__device__ __forceinline__ u32 cvtpkh(float a, float b) {  // 2xf16 packed, RTZ
  u32 r;
  asm("v_cvt_pkrtz_f16_f32 %0, %1, %2" : "=v"(r) : "v"(a), "v"(b));
  return r;
}
__device__ __forceinline__ u32 cvtpkb(float a, float b) {  // 2xbf16 packed, RNE
  u32 r;
  asm("v_cvt_pk_bf16_f32 %0, %1, %2" : "=v"(r) : "v"(a), "v"(b));
  return r;
}
__device__ __forceinline__ float bflo(u32 u) {
  return __builtin_bit_cast(float, u << 16);
}
__device__ __forceinline__ float bfhi(u32 u) {
  return __builtin_bit_cast(float, u & 0xFFFF0000u);
}

#define GLOAD16(src, dst)                                                     \
  __builtin_amdgcn_global_load_lds(                                           \
      (const __attribute__((address_space(1))) void*)(src),                   \
      (__attribute__((address_space(3))) void*)(dst), 16, 0, 0)

// ---------------- fused prep -------------------------------------------------
// blocks [0,512): K -> fp16 of (2/ln2)*K (row-swizzled tiles) + k2=||k||^2/ln2
// blocks [512,640): V -> Vt[d][k] fp16 tiles (row-swizzled)
// blocks [640,1152): Q -> fp16 row-major (no scale)
__global__ __launch_bounds__(256) void prep_kernel(
    const float* __restrict__ k, const float* __restrict__ v,
    const float* __restrict__ q, u16* __restrict__ kf_g,
    u16* __restrict__ vt_g, u16* __restrict__ qf_g, float* __restrict__ k2_g)
{
  __shared__ u16 T[64][136];
  int tid = threadIdx.x;
  if (blockIdx.x < 512) {
    int gid = blockIdx.x * 256 + tid;        // B_*M_*16 threads
    int row_g = gid >> 4;                    // b*M_ + m
    int j = gid & 15;                        // 16B chunk
    const float* kp = k + (size_t)row_g * D_ + j * 8;
    float4 a = *(const float4*)kp;
    float4 c = *(const float4*)(kp + 4);
    float xs[8] = {a.x, a.y, a.z, a.w, c.x, c.y, c.z, c.w};
    half8 kf;
    float ss = 0.f;
    #pragma unroll
    for (int e = 0; e < 8; ++e) {
      ss += xs[e] * xs[e];
      kf[e] = (_Float16)(SCALE2LOG * xs[e]);  // RNE v_cvt_f16_f32
    }
    ss += __shfl_xor(ss, 1);
    ss += __shfl_xor(ss, 2);
    ss += __shfl_xor(ss, 4);
    ss += __shfl_xor(ss, 8);
    if (j == 0) k2_g[row_g] = ss * LOG2E;
    int m = row_g & (M_ - 1);
    int b = row_g >> 11;
    int tile = m >> 6, r = m & 63;
    size_t base = ((size_t)b * NTILES + tile) * TILE_BYTES;
    u32 off = (u32)(r * 256 + j * 16) ^ ((u32)(r & 7) << 4);
    *(half8*)((char*)kf_g + base + off) = kf;
  } else if (blockIdx.x < 640) {
    int blk = blockIdx.x - 512;              // B_*NTILES blocks
    int b = blk >> 5, tile = blk & 31;
    const float* vp = v + ((size_t)b * M_ + tile * 64) * D_;
    #pragma unroll
    for (int p = 0; p < 8; ++p) {
      int idx = p * 256 + tid;
      int r = idx >> 5, c4 = idx & 31;
      float4 vv = *(const float4*)(vp + (size_t)r * D_ + c4 * 4);
      T[r][c4 * 4 + 0] = __builtin_bit_cast(u16, (_Float16)vv.x);
      T[r][c4 * 4 + 1] = __builtin_bit_cast(u16, (_Float16)vv.y);
      T[r][c4 * 4 + 2] = __builtin_bit_cast(u16, (_Float16)vv.z);
      T[r][c4 * 4 + 3] = __builtin_bit_cast(u16, (_Float16)vv.w);
    }
    __syncthreads();
    size_t base = (size_t)blk * TILE_BYTES;
    #pragma unroll
    for (int p = 0; p < 4; ++p) {
      int idx = p * 256 + tid;
      int d = idx >> 3, rb = idx & 7;
      short8 s;
      #pragma unroll
      for (int i = 0; i < 8; ++i) s[i] = (short)T[rb * 8 + i][d];
      u32 off = (u32)(d * 128 + rb * 16) ^ ((u32)(d & 7) << 4);
      *(short8*)((char*)vt_g + base + off) = s;
    }
  } else {
    int gid = (blockIdx.x - 640) * 256 + tid;  // B_*N_*16 threads
    int row_g = gid >> 4;
    int j = gid & 15;
    const float* qp = q + (size_t)row_g * D_ + j * 8;
    float4 a = *(const float4*)qp;
    float4 c = *(const float4*)(qp + 4);
    half8 qf;
    qf[0] = (_Float16)a.x; qf[1] = (_Float16)a.y;
    qf[2] = (_Float16)a.z; qf[3] = (_Float16)a.w;
    qf[4] = (_Float16)c.x; qf[5] = (_Float16)c.y;
    qf[6] = (_Float16)c.z; qf[7] = (_Float16)c.w;
    *(half8*)(qf_g + (size_t)row_g * D_ + j * 8) = qf;
  }
}

// ---------------- main attention: 8 waves x 32 q-rows (R14 core) ------------
// Prologue change only: Q loaded directly as f16 (pre-converted in prep).
__global__ __launch_bounds__(NTHREADS, 2) void rbf_attn_kernel(
    const u16* __restrict__ qf_g, const u16* __restrict__ kf_g,
    const u16* __restrict__ vt_g, const float* __restrict__ k2_g,
    float* __restrict__ out, u32* __restrict__ Opart32,
    float* __restrict__ mpart, float* __restrict__ lpart,
    int nsplit, int tiles_per_split)
{
  __shared__ __align__(16) u16 KfL[2][8192];
  __shared__ __align__(16) u16 VtL[2][8192];
  __shared__ __align__(16) float k2L[2][64];

  const int tid = threadIdx.x;
  const int w = tid >> 6;      // 0..7
  const int lane = tid & 63;
  const int qlc = lane & 31;
  const int h = lane >> 5;

  // XCD-bijective decode: all 8 q-blocks of one (b,sp) KV slice -> one XCD
  int b, qi, sp;
  {
    int gid = blockIdx.x;
    if (nsplit >= 2) {
      int xcd = gid & 7, slot = gid >> 3;
      int gpx = nsplit >> 1;               // (4*nsplit)/8 groups per XCD
      int group = xcd * gpx + (slot >> 3);
      qi = slot & 7;
      b = group & 3;
      sp = group >> 2;
    } else {
      qi = gid & 7;
      b = gid >> 3;
      sp = 0;
    }
  }
  const int qt = qi;
  const int q0 = qt * QBLK;
  const int kt0 = sp * tiles_per_split, kt1 = kt0 + tiles_per_split;

  const char* kf_b = (const char*)kf_g + (size_t)b * NTILES * TILE_BYTES;
  const char* vt_b = (const char*)vt_g + (size_t)b * NTILES * TILE_BYTES;
  const float* k2_b = k2_g + (size_t)b * M_;
  const int so = tid * 16;      // = w*1024 + lane*16, spans 8KB

  #define STAGE(buf, kt)                                                      \
    do {                                                                      \
      const char* kh_ = kf_b + (size_t)(kt) * TILE_BYTES;                     \
      const char* vt_ = vt_b + (size_t)(kt) * TILE_BYTES;                     \
      char* dk = (char*)KfL[buf];                                             \
      char* dv = (char*)VtL[buf];                                             \
      _Pragma("unroll")                                                       \
      for (int c = 0; c < 2; ++c)                                             \
        GLOAD16(kh_ + c * 8192 + so, dk + c * 8192 + w * 1024);               \
      _Pragma("unroll")                                                       \
      for (int c = 0; c < 2; ++c)                                             \
        GLOAD16(vt_ + c * 8192 + so, dv + c * 8192 + w * 1024);               \
      if (tid < 16)                                                           \
        GLOAD16((const char*)(k2_b + (kt) * KVBLK) + tid * 16,                \
                (char*)k2L[buf]);                                             \
    } while (0)

  STAGE(0, kt0);  // prologue prefetch; latency overlaps Qf loads

  // ---- Q B-frags: direct f16 loads (pre-converted), k(d) = s*16 + h*8 + j --
  half8 Qf[8];
  {
    const u16* qp = qf_g + ((size_t)b * N_ + q0 + w * 32 + qlc) * D_ + h * 8;
    #pragma unroll
    for (int s = 0; s < 8; ++s) Qf[s] = *(const half8*)(qp + s * 16);
  }

  floatx16 o[4];
  #pragma unroll
  for (int dt = 0; dt < 4; ++dt) o[dt] = (floatx16)0.0f;
  float mrun = -1e30f, lrun = 0.f;

  asm volatile("s_waitcnt vmcnt(0)" ::: "memory");
  __syncthreads();

  int pb = 0;
  for (int kt = kt0; kt < kt1; ++kt) {
    if (kt + 1 < kt1) STAGE(pb ^ 1, kt + 1);

    const char* Kb = (const char*)KfL[pb];
    const char* Vb = (const char*)VtL[pb];
    const float* k2p = k2L[pb];

    // ---- QK^T single-pass fp16 ----
    floatx16 accS0 = (floatx16)0.0f, accS1 = (floatx16)0.0f;
    __builtin_amdgcn_s_setprio(1);
    #pragma unroll
    for (int s = 0; s < 8; ++s) {
      {
        int row = qlc;
        u32 off = ((u32)(row * 256 + s * 32 + h * 16)) ^ ((u32)(row & 7) << 4);
        half8 af = *(const half8*)(Kb + off);
        accS0 = __builtin_amdgcn_mfma_f32_32x32x16_f16(af, Qf[s], accS0, 0, 0, 0);
      }
      {
        int row = 32 + qlc;
        u32 off = ((u32)(row * 256 + s * 32 + h * 16)) ^ ((u32)(row & 7) << 4);
        half8 af = *(const half8*)(Kb + off);
        accS1 = __builtin_amdgcn_mfma_f32_32x32x16_f16(af, Qf[s], accS1, 0, 0, 0);
      }
    }
    __builtin_amdgcn_s_setprio(0);

    // ---- lane-local softmax (log2 domain) ----
    float mx = -3e38f;
    #pragma unroll
    for (int ct = 0; ct < 2; ++ct) {
      #pragma unroll
      for (int g = 0; g < 4; ++g) {
        float4 kq = *(const float4*)&k2p[32 * ct + 8 * g + 4 * h];
        if (ct == 0) {
          accS0[4 * g + 0] -= kq.x; accS0[4 * g + 1] -= kq.y;
          accS0[4 * g + 2] -= kq.z; accS0[4 * g + 3] -= kq.w;
          mx = fmaxf(mx, fmaxf(fmaxf(accS0[4 * g], accS0[4 * g + 1]),
                               fmaxf(accS0[4 * g + 2], accS0[4 * g + 3])));
        } else {
          accS1[4 * g + 0] -= kq.x; accS1[4 * g + 1] -= kq.y;
          accS1[4 * g + 2] -= kq.z; accS1[4 * g + 3] -= kq.w;
          mx = fmaxf(mx, fmaxf(fmaxf(accS1[4 * g], accS1[4 * g + 1]),
                               fmaxf(accS1[4 * g + 2], accS1[4 * g + 3])));
        }
      }
    }
    mx = fmaxf(mx, __shfl_xor(mx, 32));
    if (!__all(mx - mrun <= DEFER_THR)) {
      float mnew = fmaxf(mrun, mx);
      float scl = exp2f(mrun - mnew);
      mrun = mnew;
      lrun *= scl;
      #pragma unroll
      for (int i = 0; i < 16; ++i) {
        o[0][i] *= scl; o[1][i] *= scl; o[2][i] *= scl; o[3][i] *= scl;
      }
    }
    float ls = 0.f;
    u32 W[2][4][2];
    #pragma unroll
    for (int ct = 0; ct < 2; ++ct) {
      #pragma unroll
      for (int g = 0; g < 4; ++g) {
        float p0, p1, p2, p3;
        if (ct == 0) {
          p0 = exp2f(accS0[4 * g + 0] - mrun); p1 = exp2f(accS0[4 * g + 1] - mrun);
          p2 = exp2f(accS0[4 * g + 2] - mrun); p3 = exp2f(accS0[4 * g + 3] - mrun);
        } else {
          p0 = exp2f(accS1[4 * g + 0] - mrun); p1 = exp2f(accS1[4 * g + 1] - mrun);
          p2 = exp2f(accS1[4 * g + 2] - mrun); p3 = exp2f(accS1[4 * g + 3] - mrun);
        }
        ls += (p0 + p1) + (p2 + p3);
        W[ct][g][0] = cvtpkh(p0, p1);
        W[ct][g][1] = cvtpkh(p2, p3);
      }
    }
    ls += __shfl_xor(ls, 32);
    lrun += ls;

    u32 X[2][4][2];
    #pragma unroll
    for (int ct = 0; ct < 2; ++ct)
      #pragma unroll
      for (int g = 0; g < 4; ++g) {
        X[ct][g][0] = __shfl_xor(W[ct][g][0], 32);
        X[ct][g][1] = __shfl_xor(W[ct][g][1], 32);
      }

    // ---- PV: O^T += Vt · P^T ----
    const bool h0 = (h == 0);
    __builtin_amdgcn_s_setprio(1);
    #pragma unroll
    for (int s2 = 0; s2 < 4; ++s2) {
      const int ct = s2 >> 1, e = s2 & 1;
      u32 w0 = h0 ? W[ct][2 * e][0] : X[ct][2 * e + 1][0];
      u32 w1 = h0 ? W[ct][2 * e][1] : X[ct][2 * e + 1][1];
      u32 w2 = h0 ? X[ct][2 * e][0] : W[ct][2 * e + 1][0];
      u32 w3 = h0 ? X[ct][2 * e][1] : W[ct][2 * e + 1][1];
      half8 pf = __builtin_bit_cast(half8, (u32x4){w0, w1, w2, w3});
      #pragma unroll
      for (int dt = 0; dt < 4; ++dt) {
        int row = dt * 32 + qlc;
        u32 off = ((u32)(row * 128 + s2 * 32 + h * 16)) ^ ((u32)(row & 7) << 4);
        half8 af = *(const half8*)(Vb + off);
        o[dt] = __builtin_amdgcn_mfma_f32_32x32x16_f16(af, pf, o[dt], 0, 0, 0);
      }
    }
    __builtin_amdgcn_s_setprio(0);

    asm volatile("s_waitcnt vmcnt(0)" ::: "memory");
    __syncthreads();
    pb ^= 1;
  }

  // ---- epilogue: O^T regs -> out / Opart32 packed-bf16 pairs ----
  const int qt32 = qt * 8 + w;
  if (nsplit == 1) {
    float inv = 1.0f / lrun;
    float* ob = out + ((size_t)b * N_ + q0 + w * 32 + qlc) * D_;
    #pragma unroll
    for (int dt = 0; dt < 4; ++dt)
      #pragma unroll
      for (int r = 0; r < 16; ++r) {
        int d = dt * 32 + (r & 3) + 8 * (r >> 2) + 4 * h;
        ob[d] = o[dt][r] * inv;
      }
  } else {
    // o[dt][2j],o[dt][2j+1] <-> d,d+1 with d2 = dt*16 + (j&1) + 4*(j>>1) + 2h
    u32* ob = Opart32 +
        ((((size_t)sp * B_ + b) * (N_ / 32) + qt32) * (D_ / 2)) * 32 + qlc;
    #pragma unroll
    for (int dt = 0; dt < 4; ++dt)
      #pragma unroll
      for (int j = 0; j < 8; ++j) {
        int d2 = dt * 16 + (j & 1) + 4 * (j >> 1) + 2 * h;
        ob[(size_t)d2 * 32] = cvtpkb(o[dt][2 * j], o[dt][2 * j + 1]);
      }
    if (h == 0) {
      size_t mrow = ((size_t)sp * B_ + b) * N_ + qt32 * 32 + qlc;
      mpart[mrow] = mrun;
      lpart[mrow] = lrun;
    }
  }
  #undef STAGE
}

// ---------------- split merge: 512 blocks, one (group, d-half) each ---------
__global__ __launch_bounds__(256) void rbf_reduce_kernel(
    const u32* __restrict__ Opart32, const float* __restrict__ mpart,
    const float* __restrict__ lpart, float* __restrict__ out, int nsplit)
{
  __shared__ float T2[32 * 72];
  const int t = threadIdx.x;
  const int unit = blockIdx.x;
  const int group = unit >> 1, dhalf = unit & 1;
  const int b = group >> 6, qt32 = group & 63;
  const int qln = t & 31, dg = t >> 5;           // 8 d-groups x 8 d's
  const size_t stride = (size_t)B_ * N_;
  const size_t mbase = (size_t)b * N_ + qt32 * 32 + qln;
  float mmax = -3e38f;
  for (int s = 0; s < nsplit; ++s)
    mmax = fmaxf(mmax, mpart[s * stride + mbase]);
  float acc[8];
  #pragma unroll
  for (int i = 0; i < 8; ++i) acc[i] = 0.f;
  float lsum = 0.f;
  for (int s = 0; s < nsplit; ++s) {
    float wv = exp2f(mpart[s * stride + mbase] - mmax);
    lsum += wv * lpart[s * stride + mbase];
    const u32* ob = Opart32 +
        ((((size_t)s * B_ + b) * (N_ / 32) + qt32) * (D_ / 2) +
         dhalf * 32 + dg * 4) * 32 + qln;
    #pragma unroll
    for (int i = 0; i < 4; ++i) {
      u32 u = ob[(size_t)i * 32];
      acc[2 * i + 0] += wv * bflo(u);
      acc[2 * i + 1] += wv * bfhi(u);
    }
  }
  float inv = 1.0f / lsum;
  #pragma unroll
  for (int dd = 0; dd < 8; ++dd) T2[qln * 72 + dg * 8 + dd] = acc[dd] * inv;
  __syncthreads();
  const int r = t >> 3, seg = t & 7;
  float* op = out + ((size_t)b * N_ + qt32 * 32 + r) * D_ + dhalf * 64 + seg * 8;
  float4 v0 = {T2[r * 72 + seg * 8 + 0], T2[r * 72 + seg * 8 + 1],
               T2[r * 72 + seg * 8 + 2], T2[r * 72 + seg * 8 + 3]};
  float4 v1 = {T2[r * 72 + seg * 8 + 4], T2[r * 72 + seg * 8 + 5],
               T2[r * 72 + seg * 8 + 6], T2[r * 72 + seg * 8 + 7]};
  *(float4*)op = v0;
  *(float4*)(op + 4) = v1;
}

extern "C" void kernel_launch(void* const* d_in, const int* in_sizes, int n_in,
                              void* d_out, int out_size, void* d_ws, size_t ws_size,
                              hipStream_t stream) {
  const float* q = (const float*)d_in[0];
  const float* k = (const float*)d_in[1];
  const float* v = (const float*)d_in[2];
  float* out = (float*)d_out;

  const size_t tileBytesAll = (size_t)B_ * NTILES * TILE_BYTES;  // 2 MB each
  u16* kf_g = (u16*)d_ws;
  u16* vt_g = (u16*)((char*)d_ws + tileBytesAll);
  u16* qf_g = (u16*)((char*)d_ws + 2 * tileBytesAll);            // 2 MB f16 Q
  float* k2_g = (float*)((char*)d_ws + 3 * tileBytesAll);
  const size_t prepBytes = 3 * tileBytesAll + (size_t)B_ * M_ * sizeof(float);

  const size_t perO = (size_t)B_ * N_ * D_ * sizeof(u16);   // packed bf16 pairs
  const size_t perML = 2 * (size_t)B_ * N_ * sizeof(float);
  int nsplit = SPLIT_MAX;
  while (nsplit > 1 && prepBytes + (size_t)nsplit * (perO + perML) > ws_size)
    nsplit >>= 1;

  u32* Opart32 = (u32*)((char*)d_ws + prepBytes);
  float* mpart = (float*)((char*)d_ws + prepBytes + (size_t)nsplit * perO);
  float* lpart = mpart + (size_t)nsplit * B_ * N_;
  int tiles_per_split = NTILES / nsplit;

  prep_kernel<<<1152, 256, 0, stream>>>(k, v, q, kf_g, vt_g, qf_g, k2_g);

  rbf_attn_kernel<<<dim3(8 * B_ * nsplit), NTHREADS, 0, stream>>>(
      qf_g, kf_g, vt_g, k2_g, out, Opart32, mpart, lpart, nsplit,
      tiles_per_split);
  if (nsplit > 1) {
    rbf_reduce_kernel<<<2 * B_ * (N_ / 32), 256, 0, stream>>>(
        Opart32, mpart, lpart, out, nsplit);
  }
}